// Round 5
// baseline (389.217 us; speedup 1.0000x reference)
//
#include <hip/hip_runtime.h>
#include <cstdint>
#include <climits>

static constexpr int NC   = 2000000;   // clause id range (fixed by reference)
static constexpr int NXCD = 8;
static constexpr int NCW  = (NC + 3) / 4;          // u32 words per replica (u8 x4 packed)
static constexpr int CNT_WORDS = NXCD * NCW;       // total u32 words, 16 MB

typedef int int4v __attribute__((ext_vector_type(4)));

__device__ __forceinline__ int xcc_id() {
    int x;
    asm volatile("s_getreg_b32 %0, hwreg(HW_REG_XCC_ID)" : "=s"(x));
    return x & (NXCD - 1);
}

// Zero replicas, bit-pack xb (xb = floor(xv/0.50001f), true f32 divide to match
// the reference), init the min slot.
__global__ __launch_bounds__(256) void init_k(const float* __restrict__ xv, int nv,
                                              uint8_t* __restrict__ xbb,
                                              uint32_t* __restrict__ cnt,
                                              int* __restrict__ minslot) {
    int stride = gridDim.x * blockDim.x;
    int i0 = blockIdx.x * blockDim.x + threadIdx.x;
    for (int i = i0; i < CNT_WORDS; i += stride) cnt[i] = 0u;
    int nbytes = nv >> 3;
    for (int i = i0; i < nbytes; i += stride) {
        const float* p = xv + (i << 3);
        uint32_t b = 0;
        #pragma unroll
        for (int j = 0; j < 8; ++j)
            b |= ((uint32_t)(int)floorf(p[j] / 0.50001f)) << j;
        xbb[i] = (uint8_t)b;
    }
    if (i0 == 0) {
        if (nv & 7) {
            uint32_t b = 0;
            for (int j = 0; j < (nv & 7); ++j)
                b |= ((uint32_t)(int)floorf(xv[(nbytes << 3) + j] / 0.50001f)) << j;
            xbb[nbytes] = (uint8_t)b;
        }
        *minslot = INT_MAX;
    }
}

// One polarity per launch. Counts go into the XCD-private replica via
// workgroup-scope atomics -> executed in the local (coherent-for-us) L2,
// no device-scope write-through to HBM. Replica privacy via HW_REG_XCC_ID.
template<int NEG>
__global__ __launch_bounds__(256) void edge_k(const int* __restrict__ adj,
                                              const uint32_t* __restrict__ xbw,
                                              uint32_t* __restrict__ cnt,
                                              int ne) {
    uint32_t* __restrict__ my = cnt + (size_t)xcc_id() * NCW;
    int stride = gridDim.x * blockDim.x;
    int i0 = blockIdx.x * blockDim.x + threadIdx.x;
    int n4 = ((ne & 3) == 0) ? (ne >> 2) : 0;   // vector path only if rows stay aligned
    const int4v* c4 = (const int4v*)adj;
    const int4v* v4 = (const int4v*)(adj + ne);
    for (int i = i0; i < n4; i += stride) {
        int4v c = __builtin_nontemporal_load(c4 + i);
        int4v v = __builtin_nontemporal_load(v4 + i);
        #pragma unroll
        for (int j = 0; j < 4; ++j) {
            int cc = c[j], vv = v[j];
            int b = (int)((xbw[vv >> 5] >> (vv & 31)) & 1u);
            if (b != NEG)
                __hip_atomic_fetch_add(&my[cc >> 2], 1u << ((cc & 3) * 8),
                                       __ATOMIC_RELAXED, __HIP_MEMORY_SCOPE_WORKGROUP);
        }
    }
    for (int e = (n4 << 2) + i0; e < ne; e += stride) {   // scalar tail
        int c = adj[e], v = adj[ne + e];
        int b = (int)((xbw[v >> 5] >> (v & 31)) & 1u);
        if (b != NEG)
            __hip_atomic_fetch_add(&my[c >> 2], 1u << ((c & 3) * 8),
                                   __ATOMIC_RELAXED, __HIP_MEMORY_SCOPE_WORKGROUP);
    }
}

// Sum the 8 byte-packed replicas per clause, min-reduce.
__global__ __launch_bounds__(256) void redu_k(const uint32_t* __restrict__ cnt,
                                              int* __restrict__ minslot) {
    int stride = gridDim.x * blockDim.x;
    int i0 = blockIdx.x * blockDim.x + threadIdx.x;
    int lo = INT_MAX;
    for (int w = i0; w < NCW; w += stride) {
        uint32_t s0 = 0, s1 = 0, s2 = 0, s3 = 0;
        #pragma unroll
        for (int x = 0; x < NXCD; ++x) {
            uint32_t r = cnt[(size_t)x * NCW + w];
            s0 += r & 0xffu; s1 += (r >> 8) & 0xffu;
            s2 += (r >> 16) & 0xffu; s3 += r >> 24;
        }
        int rem = NC - (w << 2);
        if (rem >= 4) {
            lo = min(lo, (int)min(min(s0, s1), min(s2, s3)));
        } else {
            if (rem > 0) lo = min(lo, (int)s0);
            if (rem > 1) lo = min(lo, (int)s1);
            if (rem > 2) lo = min(lo, (int)s2);
        }
    }
    for (int off = 32; off > 0; off >>= 1) lo = min(lo, __shfl_down(lo, off));
    if ((threadIdx.x & 63) == 0) atomicMin(minslot, lo);
}

__global__ void fin_k(const int* __restrict__ minslot, float* __restrict__ out) {
    out[0] = (float)(*minslot);
}

// ---------------- fallback path (round-2 kernel, known-good) ----------------
static constexpr size_t FB_COUNTS = 0;
static constexpr size_t FB_XB     = 8000000;
static constexpr size_t FB_MIN    = 10000000;
static constexpr int    NV_FB     = 2000000;

__global__ __launch_bounds__(256) void fb_init_k(uint32_t* __restrict__ counts,
                                                 uint8_t* __restrict__ xb,
                                                 const float* __restrict__ xv,
                                                 int* __restrict__ minslot) {
    int stride = gridDim.x * blockDim.x;
    int i0 = blockIdx.x * blockDim.x + threadIdx.x;
    for (int i = i0; i < NC; i += stride) counts[i] = 0u;
    for (int i = i0; i < NV_FB; i += stride)
        xb[i] = (uint8_t)(int)floorf(xv[i] / 0.50001f);
    if (i0 == 0) *minslot = INT_MAX;
}

template<int POS>
__global__ __launch_bounds__(256) void fb_edge_k(const int* __restrict__ adj,
                                                 const uint8_t* __restrict__ xb,
                                                 uint32_t* __restrict__ counts,
                                                 int ne) {
    int stride = gridDim.x * blockDim.x;
    int i0 = blockIdx.x * blockDim.x + threadIdx.x;
    for (int e = i0; e < ne; e += stride) {
        int c = adj[e];
        int v = adj[ne + e];
        int b = (int)xb[v];
        bool sat = POS ? (b != 0) : (b == 0);
        if (sat) atomicAdd(&counts[c], 1u);
    }
}

__global__ __launch_bounds__(256) void fb_min_k(const uint32_t* __restrict__ counts,
                                                int* __restrict__ minslot) {
    int stride = gridDim.x * blockDim.x;
    int i0 = blockIdx.x * blockDim.x + threadIdx.x;
    int lo = INT_MAX;
    for (int i = i0; i < NC; i += stride) lo = min(lo, (int)counts[i]);
    for (int off = 32; off > 0; off >>= 1) lo = min(lo, __shfl_down(lo, off));
    if ((threadIdx.x & 63) == 0) atomicMin(minslot, lo);
}

extern "C" void kernel_launch(void* const* d_in, const int* in_sizes, int n_in,
                              void* d_out, int out_size, void* d_ws, size_t ws_size,
                              hipStream_t stream) {
    const float* xv    = (const float*)d_in[0];
    const int* adj_pos = (const int*)d_in[1];   // int32 per harness contract
    const int* adj_neg = (const int*)d_in[2];
    float* out = (float*)d_out;

    const int nv   = in_sizes[0];
    const int ne_p = in_sizes[1] / 2;   // rows: [clause, var]
    const int ne_n = in_sizes[2] / 2;

    char* ws = (char*)d_ws;
    dim3 blk(256);

    const size_t cnt_by  = (size_t)CNT_WORDS * 4;                  // 16 MB
    const size_t xbb_by  = (((size_t)nv + 7) / 8 + 64) & ~63ull;   // bit-packed xb + pad
    const size_t off_xbb = cnt_by;
    const size_t off_ctl = cnt_by + xbb_by;
    const size_t need    = off_ctl + 64;

    if (ws_size >= need) {
        uint32_t* cnt  = (uint32_t*)(ws);
        uint8_t*  xbb  = (uint8_t*) (ws + off_xbb);
        int*      mins = (int*)     (ws + off_ctl);

        init_k<<<2048, blk, 0, stream>>>(xv, nv, xbb, cnt, mins);
        edge_k<0><<<2048, blk, 0, stream>>>(adj_pos, (const uint32_t*)xbb, cnt, ne_p);
        edge_k<1><<<2048, blk, 0, stream>>>(adj_neg, (const uint32_t*)xbb, cnt, ne_n);
        redu_k<<<1024, blk, 0, stream>>>(cnt, mins);
        fin_k<<<1, 1, 0, stream>>>(mins, out);
    } else {
        uint32_t* counts = (uint32_t*)(ws + FB_COUNTS);
        uint8_t*  xb     = (uint8_t*) (ws + FB_XB);
        int*      mins   = (int*)     (ws + FB_MIN);
        fb_init_k<<<2048, blk, 0, stream>>>(counts, xb, xv, mins);
        fb_edge_k<1><<<2048, blk, 0, stream>>>(adj_pos, xb, counts, ne_p);
        fb_edge_k<0><<<2048, blk, 0, stream>>>(adj_neg, xb, counts, ne_n);
        fb_min_k<<<2048, blk, 0, stream>>>(counts, mins);
        fin_k<<<1, 1, 0, stream>>>(mins, out);
    }
}

// Round 6
// 147.211 us; speedup vs baseline: 2.6439x; 2.6439x over previous
//
#include <hip/hip_runtime.h>
#include <cstdint>
#include <climits>

static constexpr int NC        = 2000000;   // clause id range (fixed by reference)
static constexpr int BIN_SHIFT = 14;
static constexpr int BINSZ     = 1 << BIN_SHIFT;            // 16384 clauses per bin
static constexpr int NBIN      = (NC + BINSZ - 1) / BINSZ;  // 123
static constexpr int NBIN_AL   = 128;                        // array rounding
static constexpr int CAPR      = 131072;    // u16 entries per bin region (2x expected)
static constexpr int CAPL      = 128;       // per-(block,bin) LDS staging entries
static constexpr int SPILLCAP  = 262144;
static constexpr int GRID_SCAT = 1024;

typedef int int4v __attribute__((ext_vector_type(4)));

// ws layout (bytes)
static constexpr size_t OFF_REG   = 0;
static constexpr size_t REG_BY    = (size_t)NBIN_AL * CAPR * 2;      // 33,554,432
static constexpr size_t OFF_SPILL = OFF_REG + REG_BY;
static constexpr size_t OFF_GCUR  = OFF_SPILL + (size_t)SPILLCAP * 4; // +1 MB
static constexpr size_t OFF_CTRL  = OFF_GCUR + (size_t)NBIN_AL * 4;
static constexpr size_t OFF_XBB   = OFF_CTRL + 64;                    // 64-aligned

// Zero cursors/ctrl, bit-pack xb (xb = floor(xv/0.50001f), true f32 divide to
// match the reference), init min slot. Regions never need clearing (read only
// up to cursor).
__global__ __launch_bounds__(256) void init_k(const float* __restrict__ xv, int nv,
                                              uint8_t* __restrict__ xbb,
                                              uint32_t* __restrict__ gcur,
                                              int* __restrict__ ctrl) {
    int stride = gridDim.x * blockDim.x;
    int i0 = blockIdx.x * blockDim.x + threadIdx.x;
    for (int i = i0; i < NBIN_AL; i += stride) gcur[i] = 0u;
    int nbytes = nv >> 3;
    for (int i = i0; i < nbytes; i += stride) {
        const float* p = xv + (i << 3);
        uint32_t b = 0;
        #pragma unroll
        for (int j = 0; j < 8; ++j)
            b |= ((uint32_t)(int)floorf(p[j] / 0.50001f)) << j;
        xbb[i] = (uint8_t)b;
    }
    if (i0 == 0) {
        if (nv & 7) {
            uint32_t b = 0;
            for (int j = 0; j < (nv & 7); ++j)
                b |= ((uint32_t)(int)floorf(xv[(nbytes << 3) + j] / 0.50001f)) << j;
            xbb[nbytes] = (uint8_t)b;
        }
        ctrl[0] = 0;        // spillCur
        ctrl[1] = INT_MAX;  // minslot
    }
}

// Scatter pass: stage satisfied clause ids per bin in LDS; flush ONCE at block
// end (one slot-reserving atomic per (block,bin), dense u16 burst copies).
// No per-edge global atomics.
__global__ __launch_bounds__(256) void scat_k(const int* __restrict__ adj_pos,
                                              const int* __restrict__ adj_neg,
                                              const uint32_t* __restrict__ xbw,
                                              uint16_t* __restrict__ regions,
                                              uint32_t* __restrict__ gcur,
                                              uint32_t* __restrict__ spill,
                                              int* __restrict__ spillCur,
                                              int ne_p, int ne_n) {
    __shared__ uint16_t buf[NBIN_AL][CAPL];   // 32 KB
    __shared__ uint32_t lcnt[NBIN_AL];
    __shared__ uint32_t lbase[NBIN_AL];
    for (int i = threadIdx.x; i < NBIN_AL; i += 256) lcnt[i] = 0u;
    __syncthreads();

    int gid = blockIdx.x * 256 + threadIdx.x;
    int gstride = GRID_SCAT * 256;

    const int* adjs[2] = {adj_pos, adj_neg};
    int nes[2] = {ne_p, ne_n};
    for (int pol = 0; pol < 2; ++pol) {
        const int* adj = adjs[pol];
        int ne = nes[pol];
        int neg = pol;
        int n4 = ((ne & 3) == 0) ? (ne >> 2) : 0;  // vector path needs aligned rows
        const int4v* c4 = (const int4v*)adj;
        const int4v* v4 = (const int4v*)(adj + ne);
        for (int i = gid; i < n4; i += gstride) {
            int4v c = __builtin_nontemporal_load(c4 + i);
            int4v v = __builtin_nontemporal_load(v4 + i);
            #pragma unroll
            for (int j = 0; j < 4; ++j) {
                int cc = c[j], vv = v[j];
                int bit = (int)((xbw[vv >> 5] >> (vv & 31)) & 1u);
                if (bit != neg) {
                    int bin = cc >> BIN_SHIFT;
                    uint32_t p = atomicAdd(&lcnt[bin], 1u);   // LDS atomic
                    if (p < (uint32_t)CAPL) buf[bin][p] = (uint16_t)(cc & (BINSZ - 1));
                    else { int g = atomicAdd(spillCur, 1);
                           if (g < SPILLCAP) spill[g] = (uint32_t)cc; }
                }
            }
        }
        for (int e = (n4 << 2) + gid; e < ne; e += gstride) {  // scalar tail
            int cc = adj[e], vv = adj[ne + e];
            int bit = (int)((xbw[vv >> 5] >> (vv & 31)) & 1u);
            if (bit != neg) {
                int bin = cc >> BIN_SHIFT;
                uint32_t p = atomicAdd(&lcnt[bin], 1u);
                if (p < (uint32_t)CAPL) buf[bin][p] = (uint16_t)(cc & (BINSZ - 1));
                else { int g = atomicAdd(spillCur, 1);
                       if (g < SPILLCAP) spill[g] = (uint32_t)cc; }
            }
        }
    }
    __syncthreads();

    // Reserve global slots (one device atomic per non-empty bin).
    for (int b = threadIdx.x; b < NBIN_AL; b += 256) {
        uint32_t n = min(lcnt[b], (uint32_t)CAPL);
        lbase[b] = n ? atomicAdd(&gcur[b], n) : 0u;
    }
    __syncthreads();

    // Wave-cooperative dense copy; region overflow routed exactly to spill.
    int wave = threadIdx.x >> 6, lane = threadIdx.x & 63;
    for (int b = wave; b < NBIN_AL; b += 4) {
        uint32_t n = min(lcnt[b], (uint32_t)CAPL);
        uint32_t base = lbase[b];
        uint16_t* rb = regions + (size_t)b * CAPR;
        for (uint32_t i = lane; i < n; i += 64) {
            uint32_t dst = base + i;
            if (dst < (uint32_t)CAPR) rb[dst] = buf[b][i];
            else { int g = atomicAdd(spillCur, 1);
                   if (g < SPILLCAP)
                       spill[g] = ((uint32_t)b << BIN_SHIFT) | (uint32_t)buf[b][i]; }
        }
    }
}

// Histogram pass: one block per bin, 64 KB LDS counters, min-reduce.
__global__ __launch_bounds__(256) void hist_k(const uint16_t* __restrict__ regions,
                                              const uint32_t* __restrict__ gcur,
                                              const uint32_t* __restrict__ spill,
                                              const int* __restrict__ ctrl,
                                              int* __restrict__ minslot) {
    __shared__ uint32_t hist[BINSZ];   // 64 KB
    int b = blockIdx.x;
    for (int i = threadIdx.x; i < BINSZ; i += 256) hist[i] = 0u;
    __syncthreads();

    uint32_t n = min(gcur[b], (uint32_t)CAPR);
    const uint16_t* rb = regions + (size_t)b * CAPR;
    const uint32_t* r32 = (const uint32_t*)rb;     // region base is 256KB-aligned
    uint32_t n2 = n >> 1;
    for (uint32_t i = threadIdx.x; i < n2; i += 256) {
        uint32_t w = r32[i];
        atomicAdd(&hist[w & 0xffffu], 1u);
        atomicAdd(&hist[w >> 16], 1u);
    }
    if ((n & 1u) && threadIdx.x == 0) atomicAdd(&hist[rb[n - 1]], 1u);

    int sn = min(ctrl[0], SPILLCAP);
    for (int i = threadIdx.x; i < sn; i += 256) {
        uint32_t c = spill[i];
        if ((int)(c >> BIN_SHIFT) == b) atomicAdd(&hist[c & (BINSZ - 1)], 1u);
    }
    __syncthreads();

    int base = b << BIN_SHIFT;
    int lim = min(BINSZ, NC - base);
    int lo = INT_MAX;
    for (int i = threadIdx.x; i < lim; i += 256) lo = min(lo, (int)hist[i]);
    for (int off = 32; off > 0; off >>= 1) lo = min(lo, __shfl_down(lo, off));
    if ((threadIdx.x & 63) == 0) atomicMin(minslot, lo);
}

__global__ void fin_k(const int* __restrict__ minslot, float* __restrict__ out) {
    out[0] = (float)(*minslot);
}

// ---------------- fallback path (round-2 kernel, known-good) ----------------
static constexpr size_t FB_COUNTS = 0;
static constexpr size_t FB_XB     = 8000000;
static constexpr size_t FB_MIN    = 10000000;
static constexpr int    NV_FB     = 2000000;

__global__ __launch_bounds__(256) void fb_init_k(uint32_t* __restrict__ counts,
                                                 uint8_t* __restrict__ xb,
                                                 const float* __restrict__ xv,
                                                 int* __restrict__ minslot) {
    int stride = gridDim.x * blockDim.x;
    int i0 = blockIdx.x * blockDim.x + threadIdx.x;
    for (int i = i0; i < NC; i += stride) counts[i] = 0u;
    for (int i = i0; i < NV_FB; i += stride)
        xb[i] = (uint8_t)(int)floorf(xv[i] / 0.50001f);
    if (i0 == 0) *minslot = INT_MAX;
}

template<int POS>
__global__ __launch_bounds__(256) void fb_edge_k(const int* __restrict__ adj,
                                                 const uint8_t* __restrict__ xb,
                                                 uint32_t* __restrict__ counts,
                                                 int ne) {
    int stride = gridDim.x * blockDim.x;
    int i0 = blockIdx.x * blockDim.x + threadIdx.x;
    for (int e = i0; e < ne; e += stride) {
        int c = adj[e];
        int v = adj[ne + e];
        int b = (int)xb[v];
        bool sat = POS ? (b != 0) : (b == 0);
        if (sat) atomicAdd(&counts[c], 1u);
    }
}

__global__ __launch_bounds__(256) void fb_min_k(const uint32_t* __restrict__ counts,
                                                int* __restrict__ minslot) {
    int stride = gridDim.x * blockDim.x;
    int i0 = blockIdx.x * blockDim.x + threadIdx.x;
    int lo = INT_MAX;
    for (int i = i0; i < NC; i += stride) lo = min(lo, (int)counts[i]);
    for (int off = 32; off > 0; off >>= 1) lo = min(lo, __shfl_down(lo, off));
    if ((threadIdx.x & 63) == 0) atomicMin(minslot, lo);
}

extern "C" void kernel_launch(void* const* d_in, const int* in_sizes, int n_in,
                              void* d_out, int out_size, void* d_ws, size_t ws_size,
                              hipStream_t stream) {
    const float* xv    = (const float*)d_in[0];
    const int* adj_pos = (const int*)d_in[1];   // int32 per harness contract
    const int* adj_neg = (const int*)d_in[2];
    float* out = (float*)d_out;

    const int nv   = in_sizes[0];
    const int ne_p = in_sizes[1] / 2;   // rows: [clause, var]
    const int ne_n = in_sizes[2] / 2;

    char* ws = (char*)d_ws;
    dim3 blk(256);

    const size_t xbb_by = ((size_t)(nv + 7) / 8 + 64) & ~63ull;
    const size_t need   = OFF_XBB + xbb_by;

    if (ws_size >= need) {
        uint16_t* regions = (uint16_t*)(ws + OFF_REG);
        uint32_t* spill   = (uint32_t*)(ws + OFF_SPILL);
        uint32_t* gcur    = (uint32_t*)(ws + OFF_GCUR);
        int*      ctrl    = (int*)     (ws + OFF_CTRL);   // [0]=spillCur [1]=minslot
        uint8_t*  xbb     = (uint8_t*) (ws + OFF_XBB);

        init_k<<<2048, blk, 0, stream>>>(xv, nv, xbb, gcur, ctrl);
        scat_k<<<GRID_SCAT, blk, 0, stream>>>(adj_pos, adj_neg, (const uint32_t*)xbb,
                                              regions, gcur, spill, ctrl, ne_p, ne_n);
        hist_k<<<NBIN, blk, 0, stream>>>(regions, gcur, spill, ctrl, ctrl + 1);
        fin_k<<<1, 1, 0, stream>>>(ctrl + 1, out);
    } else {
        uint32_t* counts = (uint32_t*)(ws + FB_COUNTS);
        uint8_t*  xb     = (uint8_t*) (ws + FB_XB);
        int*      mins   = (int*)     (ws + FB_MIN);
        fb_init_k<<<2048, blk, 0, stream>>>(counts, xb, xv, mins);
        fb_edge_k<1><<<2048, blk, 0, stream>>>(adj_pos, xb, counts, ne_p);
        fb_edge_k<0><<<2048, blk, 0, stream>>>(adj_neg, xb, counts, ne_n);
        fb_min_k<<<2048, blk, 0, stream>>>(counts, mins);
        fin_k<<<1, 1, 0, stream>>>(mins, out);
    }
}